// Round 4
// baseline (1106.084 us; speedup 1.0000x reference)
//
#include <hip/hip_runtime.h>
#include <math.h>

typedef __attribute__((ext_vector_type(8))) short s8v;   // 8 x bf16
typedef __attribute__((ext_vector_type(4))) short s4v;   // 4 x bf16
typedef __attribute__((ext_vector_type(4))) float f4v;   // 4 x f32

static __device__ __forceinline__ unsigned short f2bf(float f) {
    union { float f; unsigned int u; } v; v.f = f;
    unsigned int r = v.u + 0x7fffu + ((v.u >> 16) & 1u);   // RNE
    return (unsigned short)(r >> 16);
}

// ---------- weight conversion: Wh[1],Wh[2] and Wout to bf16 ----------
__global__ void conv_bf16(const float* __restrict__ Wh, const float* __restrict__ Wout,
                          unsigned short* __restrict__ whbf, unsigned short* __restrict__ woutbf) {
    int i = blockIdx.x * 256 + threadIdx.x;
    if (i < 524288) {
        whbf[i] = f2bf(Wh[262144 + i]);            // layers 1,2 contiguous
    } else if (i < 524288 + 32768) {
        int j = i - 524288;
        woutbf[j] = f2bf(Wout[j]);
    }
}

// ---------- G0 = Wh0 @ W_in (512x64) fp32, + transposed bf16 copy ----------
__global__ void g0_kernel(const float* __restrict__ Wh0, const float* __restrict__ Win,
                          float* __restrict__ G0, unsigned short* __restrict__ G0tb) {
    int i = blockIdx.x;      // 0..511
    int j = threadIdx.x;     // 0..63
    float acc = 0.f;
    for (int k = 0; k < 512; ++k)
        acc = fmaf(Wh0[i * 512 + k], Win[k * 64 + j], acc);
    G0[i * 64 + j] = acc;
    G0tb[j * 512 + i] = f2bf(acc);
}

// ---------- fp32 GEMM, branch-fused over blockIdx.z ----------
// C[4096][N] = X(MxK,ldx) @ W(NxK,ldw)^T ; tile 128x64, 256 thr, 8x4 micro.
// mode bits: 1=+bias  2=relu  4=write C  8=write mask(u8)  16=mul by maskMul(u8)
__global__ __launch_bounds__(256) void gemm_nt(
    const float* __restrict__ X0, const float* __restrict__ X1, int ldx,
    const float* __restrict__ W, int ldw,
    const float* __restrict__ bias,
    float* __restrict__ C0, float* __restrict__ C1, int ldc,
    unsigned char* __restrict__ mo0, unsigned char* __restrict__ mo1,
    const unsigned char* __restrict__ mm0, const unsigned char* __restrict__ mm1,
    int K, int N, int mode)
{
    const int z = blockIdx.z;
    const float* __restrict__ X = z ? X1 : X0;
    float* __restrict__ C = z ? C1 : C0;
    unsigned char* __restrict__ maskOut = z ? mo1 : mo0;
    const unsigned char* __restrict__ maskMul = z ? mm1 : mm0;

    __shared__ float Xs[32][132];
    __shared__ float Ws[32][68];
    const int tid = threadIdx.x;
    const int m0 = blockIdx.x * 128;
    const int n0 = blockIdx.y * 64;
    const int tx = tid & 15, ty = tid >> 4;
    float acc[8][4] = {};

    float4 xr[4], wr[2];

    #define LOADCHUNK(k0)                                                        \
        {                                                                        \
            _Pragma("unroll")                                                    \
            for (int r = 0; r < 4; ++r) {                                        \
                int idx = tid + r * 256;                                         \
                int row = idx >> 3, kq = (idx & 7) * 4;                          \
                xr[r] = *(const float4*)(X + (size_t)(m0 + row) * ldx + (k0) + kq); \
            }                                                                    \
            _Pragma("unroll")                                                    \
            for (int r = 0; r < 2; ++r) {                                        \
                int idx = tid + r * 256;                                         \
                int row = idx >> 3, kq = (idx & 7) * 4;                          \
                wr[r] = *(const float4*)(W + (size_t)(n0 + row) * ldw + (k0) + kq); \
            }                                                                    \
        }
    #define STASH()                                                              \
        {                                                                        \
            _Pragma("unroll")                                                    \
            for (int r = 0; r < 4; ++r) {                                        \
                int idx = tid + r * 256;                                         \
                int row = idx >> 3, kq = (idx & 7) * 4;                          \
                Xs[kq + 0][row] = xr[r].x; Xs[kq + 1][row] = xr[r].y;            \
                Xs[kq + 2][row] = xr[r].z; Xs[kq + 3][row] = xr[r].w;            \
            }                                                                    \
            _Pragma("unroll")                                                    \
            for (int r = 0; r < 2; ++r) {                                        \
                int idx = tid + r * 256;                                         \
                int row = idx >> 3, kq = (idx & 7) * 4;                          \
                Ws[kq + 0][row] = wr[r].x; Ws[kq + 1][row] = wr[r].y;            \
                Ws[kq + 2][row] = wr[r].z; Ws[kq + 3][row] = wr[r].w;            \
            }                                                                    \
        }

    LOADCHUNK(0);
    STASH();
    __syncthreads();

    for (int k0 = 0; k0 < K; k0 += 32) {
        bool last = (k0 + 32 >= K);
        if (!last) LOADCHUNK(k0 + 32);
        #pragma unroll
        for (int kk = 0; kk < 32; ++kk) {
            float4 a0 = *(const float4*)&Xs[kk][ty * 4];
            float4 a1 = *(const float4*)&Xs[kk][64 + ty * 4];
            float4 b0 = *(const float4*)&Ws[kk][tx * 4];
            float av[8] = {a0.x, a0.y, a0.z, a0.w, a1.x, a1.y, a1.z, a1.w};
            float bv[4] = {b0.x, b0.y, b0.z, b0.w};
            #pragma unroll
            for (int i = 0; i < 8; ++i)
                #pragma unroll
                for (int j = 0; j < 4; ++j)
                    acc[i][j] = fmaf(av[i], bv[j], acc[i][j]);
        }
        __syncthreads();
        if (!last) {
            STASH();
            __syncthreads();
        }
    }

    float4 bb = {0, 0, 0, 0};
    if (mode & 1) bb = *(const float4*)(bias + n0 + tx * 4);
    const int c0 = n0 + tx * 4;
    #pragma unroll
    for (int i = 0; i < 8; ++i) {
        int r = m0 + ((i < 4) ? (ty * 4 + i) : (64 + ty * 4 + (i - 4)));
        float v[4];
        #pragma unroll
        for (int j = 0; j < 4; ++j) {
            v[j] = acc[i][j];
            if (mode & 1) v[j] += ((const float*)&bb)[j];
        }
        if (mode & 8) {
            uchar4 mo;
            mo.x = v[0] > 0.0f; mo.y = v[1] > 0.0f; mo.z = v[2] > 0.0f; mo.w = v[3] > 0.0f;
            *(uchar4*)&maskOut[(size_t)r * N + c0] = mo;
        }
        if (mode & 16) {
            uchar4 mm = *(const uchar4*)&maskMul[(size_t)r * N + c0];
            v[0] *= mm.x; v[1] *= mm.y; v[2] *= mm.z; v[3] *= mm.w;
        }
        if (mode & 2) {
            #pragma unroll
            for (int j = 0; j < 4; ++j) v[j] = fmaxf(v[j], 0.0f);
        }
        if (mode & 4) {
            float4 st = {v[0], v[1], v[2], v[3]};
            *(float4*)(C + (size_t)r * ldc + c0) = st;
        }
    }
}

// ---------- zng: bf16 MFMA Jacobian chain, 1 batch elem / block ----------
// 512 threads, 8 waves, ~68 KB LDS; slim registers (no A double-buffer) so
// (512,4) => <=128 VGPR => 2 blocks/CU (16 waves/CU).
__global__ __launch_bounds__(512, 4) void zng_kernel(
    const unsigned short* __restrict__ whbf,   // [2][512][512] bf16 (layers 1,2)
    const unsigned short* __restrict__ woutbf, // [64][512] bf16
    const unsigned short* __restrict__ G0tb,   // [64][512] bf16 (G0 transposed)
    const unsigned char* __restrict__ mz1,
    const unsigned char* __restrict__ mz2,
    const unsigned char* __restrict__ mz3,
    float* __restrict__ out)                   // (4096,192), writes cols 128..191
{
    __shared__ __align__(16) unsigned short Rt[64 * 520]; // R^T: [n][k]
    __shared__ unsigned char m2s[512];
    __shared__ unsigned char m3s[512];

    const int b   = blockIdx.x;
    const int tid = threadIdx.x;

    m2s[tid] = mz2[(size_t)b * 512 + tid];
    m3s[tid] = mz3[(size_t)b * 512 + tid];

    // Phase A: Rt[n][k] = bf16(G0t[n][k]) * D1[k], vectorized x8
    #pragma unroll
    for (int i = 0; i < 8; ++i) {
        int idx = i * 512 + tid;           // 0..4095
        int n = idx >> 6, k = (idx & 63) * 8;
        s8v g = *(const s8v*)(G0tb + n * 512 + k);
        const unsigned char* mm = mz1 + (size_t)b * 512 + k;
        unsigned int mlo = *(const unsigned int*)(mm);
        unsigned int mhi = *(const unsigned int*)(mm + 4);
        s8v r;
        #pragma unroll
        for (int j = 0; j < 4; ++j) r[j] = ((mlo >> (8 * j)) & 1) ? g[j] : (short)0;
        #pragma unroll
        for (int j = 0; j < 4; ++j) r[4 + j] = ((mhi >> (8 * j)) & 1) ? g[4 + j] : (short)0;
        *(s8v*)(&Rt[n * 520 + k]) = r;
    }
    __syncthreads();

    const int lane = tid & 63, wave = tid >> 6;
    const int q = lane >> 4, ln = lane & 15;

    // stages: Out = Wh[s+1] @ R ; R <- (D[s+2] (.) Out)^T
    for (int s = 0; s < 2; ++s) {
        const unsigned short* A = whbf + (size_t)s * 262144;
        f4v acc[4][4];
        #pragma unroll
        for (int mt = 0; mt < 4; ++mt)
            #pragma unroll
            for (int nt = 0; nt < 4; ++nt)
                acc[mt][nt] = (f4v)(0.0f);

        for (int ks = 0; ks < 16; ++ks) {
            int kk = ks * 32 + q * 8;
            s8v af[4], bfr[4];
            #pragma unroll
            for (int mt = 0; mt < 4; ++mt)
                af[mt] = *(const s8v*)(A + (size_t)(wave * 64 + mt * 16 + ln) * 512 + kk);
            #pragma unroll
            for (int nt = 0; nt < 4; ++nt)
                bfr[nt] = *(const s8v*)(&Rt[(nt * 16 + ln) * 520 + kk]);
            #pragma unroll
            for (int mt = 0; mt < 4; ++mt)
                #pragma unroll
                for (int nt = 0; nt < 4; ++nt)
                    acc[mt][nt] = __builtin_amdgcn_mfma_f32_16x16x32_bf16(af[mt], bfr[nt], acc[mt][nt], 0, 0, 0);
        }
        __syncthreads();   // all reads of old Rt done

        const unsigned char* msk = (s == 0) ? m2s : m3s;
        #pragma unroll
        for (int mt = 0; mt < 4; ++mt) {
            int m0 = wave * 64 + mt * 16 + q * 4;
            uchar4 mv = *(const uchar4*)&msk[m0];
            unsigned char mb[4] = {mv.x, mv.y, mv.z, mv.w};
            #pragma unroll
            for (int nt = 0; nt < 4; ++nt) {
                int n = nt * 16 + ln;
                s4v pk;
                #pragma unroll
                for (int r = 0; r < 4; ++r) {
                    float v = mb[r] ? acc[mt][nt][r] : 0.0f;
                    pk[r] = (short)f2bf(v);
                }
                *(s4v*)(&Rt[n * 520 + m0]) = pk;
            }
        }
        __syncthreads();
    }

    // final: g = Wout @ R3 (64x64); zng[m] = ||g[m,:]|| — R2-validated form,
    // waves 0..3 each do the full K for 16 output rows; waves 4..7 idle.
    if (wave < 4) {
        const int w4 = wave;
        f4v acc3[4];
        #pragma unroll
        for (int nt = 0; nt < 4; ++nt) acc3[nt] = (f4v)(0.0f);
        for (int ks = 0; ks < 16; ++ks) {
            int kA = ks * 32 + q * 8;
            s8v af = *(const s8v*)(woutbf + (size_t)(w4 * 16 + ln) * 512 + kA);
            #pragma unroll
            for (int nt = 0; nt < 4; ++nt) {
                s8v bfr = *(const s8v*)(&Rt[(nt * 16 + ln) * 520 + kA]);
                acc3[nt] = __builtin_amdgcn_mfma_f32_16x16x32_bf16(af, bfr, acc3[nt], 0, 0, 0);
            }
        }
        float ss[4];
        #pragma unroll
        for (int r = 0; r < 4; ++r) {
            float s = 0.f;
            #pragma unroll
            for (int nt = 0; nt < 4; ++nt) { float v = acc3[nt][r]; s = fmaf(v, v, s); }
            ss[r] = s;
        }
        #pragma unroll
        for (int off = 1; off < 16; off <<= 1)
            #pragma unroll
            for (int r = 0; r < 4; ++r)
                ss[r] += __shfl_xor(ss[r], off, 64);
        if (ln == 0) {
            #pragma unroll
            for (int r = 0; r < 4; ++r)
                out[(size_t)b * 192 + 128 + w4 * 16 + q * 4 + r] = sqrtf(ss[r]);
        }
    }
}

// ---------- host ----------
extern "C" void kernel_launch(void* const* d_in, const int* in_sizes, int n_in,
                              void* d_out, int out_size, void* d_ws, size_t ws_size,
                              hipStream_t stream) {
    const float* x    = (const float*)d_in[0];
    const float* Win  = (const float*)d_in[1];
    const float* bin  = (const float*)d_in[2];
    const float* Wh   = (const float*)d_in[3];
    const float* bh   = (const float*)d_in[4];
    const float* Wout = (const float*)d_in[5];
    const float* bout = (const float*)d_in[6];
    float* out = (float*)d_out;

    char* ws = (char*)d_ws;
    float*          G0     = (float*)(ws);                         // 131072 B
    unsigned short* G0tb   = (unsigned short*)(ws + 131072);       // 65536 B
    unsigned short* whbf   = (unsigned short*)(ws + 196608);       // 1048576 B
    unsigned short* woutbf = (unsigned short*)(ws + 1245184);      // 65536 B
    unsigned char*  masks  = (unsigned char*)(ws + 1310720);       // 6 * 2 MB
    unsigned char* mt1 = masks + 0 * 2097152;
    unsigned char* mt2 = masks + 1 * 2097152;
    unsigned char* mt3 = masks + 2 * 2097152;
    unsigned char* mz1 = masks + 3 * 2097152;
    unsigned char* mz2 = masks + 4 * 2097152;
    unsigned char* mz3 = masks + 5 * 2097152;
    float* bufs = (float*)(ws + 1310720 + 12582912);               // 4 x 8 MB
    float* tA = bufs + 0 * 2097152;
    float* tB = bufs + 1 * 2097152;
    float* zA = bufs + 2 * 2097152;
    float* zB = bufs + 3 * 2097152;

    const float* Wh0 = Wh;
    const float* Wh1 = Wh + 262144;
    const float* Wh2 = Wh + 524288;
    const float* bh0 = bh, *bh1 = bh + 512, *bh2 = bh + 1024;

    conv_bf16<<<dim3(2176), dim3(256), 0, stream>>>(Wh, Wout, whbf, woutbf);
    g0_kernel<<<dim3(512), dim3(64), 0, stream>>>(Wh0, Win, G0, G0tb);

    // fused 2-branch GEMM launcher (Z=2) and single-branch (Z=1)
    auto gemm2 = [&](const float* X0, const float* X1, int ldx,
                     const float* W, int ldw, const float* bias,
                     float* C0, float* C1, int ldc,
                     unsigned char* mo0, unsigned char* mo1,
                     const unsigned char* mm0, const unsigned char* mm1,
                     int K, int N, int mode) {
        dim3 g(4096 / 128, N / 64, 2);
        gemm_nt<<<g, dim3(256), 0, stream>>>(X0, X1, ldx, W, ldw, bias, C0, C1, ldc,
                                             mo0, mo1, mm0, mm1, K, N, mode);
    };
    auto gemm1 = [&](const float* X, int ldx, const float* W, int ldw, const float* bias,
                     float* C, int ldc, unsigned char* mo, const unsigned char* mm,
                     int K, int N, int mode) {
        dim3 g(4096 / 128, N / 64, 1);
        gemm_nt<<<g, dim3(256), 0, stream>>>(X, 0, ldx, W, ldw, bias, C, 0, ldc,
                                             mo, 0, mm, 0, K, N, mode);
    };

    // ---- fused forward + delta chain (t: x[:,0:64] ; z: x[:,128:192]) ----
    gemm2(x, x + 128, 192, Win, 64, bin, tA, zA, 512, 0, 0, 0, 0, 64, 512, 1 | 4);          // h0
    gemm2(tA, zA, 512, Wh0, 512, bh0,    tB, zB, 512, 0, 0, 0, 0, 512, 512, 1 | 2 | 4);     // h1
    gemm2(tB, zB, 512, Wh0, 512, bh0,    0, 0, 0, mt1, mz1, 0, 0, 512, 512, 1 | 8);         // delta1
    gemm2(tB, zB, 512, Wh1, 512, bh1,    tA, zA, 512, 0, 0, 0, 0, 512, 512, 1 | 2 | 4);     // h2
    gemm2(tA, zA, 512, Wh1, 512, bh1,    0, 0, 0, mt2, mz2, 0, 0, 512, 512, 1 | 8);         // delta2
    gemm2(tA, zA, 512, Wh2, 512, bh2,    tB, zB, 512, 0, 0, 0, 0, 512, 512, 1 | 2 | 4);     // h3
    gemm2(tB, zB, 512, Wh2, 512, bh2,    0, 0, 0, mt3, mz3, 0, 0, 512, 512, 1 | 8);         // delta3

    // ---- zng (z-branch Jacobian row norms) ----
    zng_kernel<<<dim3(4096), dim3(512), 0, stream>>>(whbf, woutbf, G0tb, mz1, mz2, mz3, out);

    // ---- h_out (t-branch forward output) ----
    gemm1(tB, 512, Wout, 512, bout, out, 192, 0, 0, 512, 64, 1 | 4);                        // cols 0..63

    // ---- h_dot chain: V = D (.) (W v), contracted with xtdot up-front ----
    gemm1(x + 64, 192, G0, 64, 0, tA, 512, 0, mt1, 64, 512, 4 | 16);                        // V1
    gemm1(tA, 512, Wh1, 512, 0, zA, 512, 0, mt2, 512, 512, 4 | 16);                         // V2
    gemm1(zA, 512, Wh2, 512, 0, zB, 512, 0, mt3, 512, 512, 4 | 16);                         // V3
    gemm1(zB, 512, Wout, 512, 0, out + 64, 192, 0, 0, 512, 64, 4);                          // h_dot
}

// Round 5
// 1030.185 us; speedup vs baseline: 1.0737x; 1.0737x over previous
//
#include <hip/hip_runtime.h>
#include <math.h>

typedef __attribute__((ext_vector_type(8))) short s8v;   // 8 x bf16
typedef __attribute__((ext_vector_type(4))) short s4v;   // 4 x bf16
typedef __attribute__((ext_vector_type(4))) float f4v;   // 4 x f32

static __device__ __forceinline__ unsigned short f2bf(float f) {
    union { float f; unsigned int u; } v; v.f = f;
    unsigned int r = v.u + 0x7fffu + ((v.u >> 16) & 1u);   // RNE
    return (unsigned short)(r >> 16);
}

// ---------- weight conversion: Wh[1],Wh[2] and Wout to bf16 ----------
__global__ void conv_bf16(const float* __restrict__ Wh, const float* __restrict__ Wout,
                          unsigned short* __restrict__ whbf, unsigned short* __restrict__ woutbf) {
    int i = blockIdx.x * 256 + threadIdx.x;
    if (i < 524288) {
        whbf[i] = f2bf(Wh[262144 + i]);            // layers 1,2 contiguous
    } else if (i < 524288 + 32768) {
        int j = i - 524288;
        woutbf[j] = f2bf(Wout[j]);
    }
}

// ---------- G0 = Wh0 @ W_in (512x64) fp32, + transposed bf16 copy ----------
__global__ void g0_kernel(const float* __restrict__ Wh0, const float* __restrict__ Win,
                          float* __restrict__ G0, unsigned short* __restrict__ G0tb) {
    int i = blockIdx.x;      // 0..511
    int j = threadIdx.x;     // 0..63
    float acc = 0.f;
    for (int k = 0; k < 512; ++k)
        acc = fmaf(Wh0[i * 512 + k], Win[k * 64 + j], acc);
    G0[i * 64 + j] = acc;
    G0tb[j * 512 + i] = f2bf(acc);
}

// ======== fp32 GEMM 128x64 tile (validated R4) — used for N=64 outputs ========
// mode bits: 1=+bias  2=relu  4=write C  8=write mask(u8)  16=mul by maskMul(u8)
__global__ __launch_bounds__(256) void gemm_nt(
    const float* __restrict__ X0, const float* __restrict__ X1, int ldx,
    const float* __restrict__ W, int ldw,
    const float* __restrict__ bias,
    float* __restrict__ C0, float* __restrict__ C1, int ldc,
    unsigned char* __restrict__ mo0, unsigned char* __restrict__ mo1,
    const unsigned char* __restrict__ mm0, const unsigned char* __restrict__ mm1,
    int K, int N, int mode)
{
    const int z = blockIdx.z;
    const float* __restrict__ X = z ? X1 : X0;
    float* __restrict__ C = z ? C1 : C0;
    unsigned char* __restrict__ maskOut = z ? mo1 : mo0;
    const unsigned char* __restrict__ maskMul = z ? mm1 : mm0;

    __shared__ float Xs[32][132];
    __shared__ float Ws[32][68];
    const int tid = threadIdx.x;
    const int m0 = blockIdx.x * 128;
    const int n0 = blockIdx.y * 64;
    const int tx = tid & 15, ty = tid >> 4;
    float acc[8][4] = {};

    float4 xr[4], wr[2];

    #define LOADCHUNK(k0)                                                        \
        {                                                                        \
            _Pragma("unroll")                                                    \
            for (int r = 0; r < 4; ++r) {                                        \
                int idx = tid + r * 256;                                         \
                int row = idx >> 3, kq = (idx & 7) * 4;                          \
                xr[r] = *(const float4*)(X + (size_t)(m0 + row) * ldx + (k0) + kq); \
            }                                                                    \
            _Pragma("unroll")                                                    \
            for (int r = 0; r < 2; ++r) {                                        \
                int idx = tid + r * 256;                                         \
                int row = idx >> 3, kq = (idx & 7) * 4;                          \
                wr[r] = *(const float4*)(W + (size_t)(n0 + row) * ldw + (k0) + kq); \
            }                                                                    \
        }
    #define STASH()                                                              \
        {                                                                        \
            _Pragma("unroll")                                                    \
            for (int r = 0; r < 4; ++r) {                                        \
                int idx = tid + r * 256;                                         \
                int row = idx >> 3, kq = (idx & 7) * 4;                          \
                Xs[kq + 0][row] = xr[r].x; Xs[kq + 1][row] = xr[r].y;            \
                Xs[kq + 2][row] = xr[r].z; Xs[kq + 3][row] = xr[r].w;            \
            }                                                                    \
            _Pragma("unroll")                                                    \
            for (int r = 0; r < 2; ++r) {                                        \
                int idx = tid + r * 256;                                         \
                int row = idx >> 3, kq = (idx & 7) * 4;                          \
                Ws[kq + 0][row] = wr[r].x; Ws[kq + 1][row] = wr[r].y;            \
                Ws[kq + 2][row] = wr[r].z; Ws[kq + 3][row] = wr[r].w;            \
            }                                                                    \
        }

    LOADCHUNK(0);
    STASH();
    __syncthreads();

    for (int k0 = 0; k0 < K; k0 += 32) {
        bool last = (k0 + 32 >= K);
        if (!last) LOADCHUNK(k0 + 32);
        #pragma unroll
        for (int kk = 0; kk < 32; ++kk) {
            float4 a0 = *(const float4*)&Xs[kk][ty * 4];
            float4 a1 = *(const float4*)&Xs[kk][64 + ty * 4];
            float4 b0 = *(const float4*)&Ws[kk][tx * 4];
            float av[8] = {a0.x, a0.y, a0.z, a0.w, a1.x, a1.y, a1.z, a1.w};
            float bv[4] = {b0.x, b0.y, b0.z, b0.w};
            #pragma unroll
            for (int i = 0; i < 8; ++i)
                #pragma unroll
                for (int j = 0; j < 4; ++j)
                    acc[i][j] = fmaf(av[i], bv[j], acc[i][j]);
        }
        __syncthreads();
        if (!last) {
            STASH();
            __syncthreads();
        }
    }

    float4 bb = {0, 0, 0, 0};
    if (mode & 1) bb = *(const float4*)(bias + n0 + tx * 4);
    const int c0 = n0 + tx * 4;
    #pragma unroll
    for (int i = 0; i < 8; ++i) {
        int r = m0 + ((i < 4) ? (ty * 4 + i) : (64 + ty * 4 + (i - 4)));
        float v[4];
        #pragma unroll
        for (int j = 0; j < 4; ++j) {
            v[j] = acc[i][j];
            if (mode & 1) v[j] += ((const float*)&bb)[j];
        }
        if (mode & 8) {
            uchar4 mo;
            mo.x = v[0] > 0.0f; mo.y = v[1] > 0.0f; mo.z = v[2] > 0.0f; mo.w = v[3] > 0.0f;
            *(uchar4*)&maskOut[(size_t)r * N + c0] = mo;
        }
        if (mode & 16) {
            uchar4 mm = *(const uchar4*)&maskMul[(size_t)r * N + c0];
            v[0] *= mm.x; v[1] *= mm.y; v[2] *= mm.z; v[3] *= mm.w;
        }
        if (mode & 2) {
            #pragma unroll
            for (int j = 0; j < 4; ++j) v[j] = fmaxf(v[j], 0.0f);
        }
        if (mode & 4) {
            float4 st = {v[0], v[1], v[2], v[3]};
            *(float4*)(C + (size_t)r * ldc + c0) = st;
        }
    }
}

// ======== fp32 GEMM 128x128 tile, 8x8 micro — main ladder kernel ========
__global__ __launch_bounds__(256) void gemm_nt128(
    const float* __restrict__ X0, const float* __restrict__ X1, int ldx,
    const float* __restrict__ W, int ldw,
    const float* __restrict__ bias,
    float* __restrict__ C0, float* __restrict__ C1, int ldc,
    unsigned char* __restrict__ mo0, unsigned char* __restrict__ mo1,
    const unsigned char* __restrict__ mm0, const unsigned char* __restrict__ mm1,
    int K, int N, int mode)
{
    const int z = blockIdx.z;
    const float* __restrict__ X = z ? X1 : X0;
    float* __restrict__ C = z ? C1 : C0;
    unsigned char* __restrict__ maskOut = z ? mo1 : mo0;
    const unsigned char* __restrict__ maskMul = z ? mm1 : mm0;

    __shared__ float Xs[32][132];
    __shared__ float Ws[32][132];
    const int tid = threadIdx.x;
    const int m0 = blockIdx.x * 128;
    const int n0 = blockIdx.y * 128;
    const int tx = tid & 15, ty = tid >> 4;
    float acc[8][8] = {};

    float4 xr[4], wr[4];

    #define LOADCHUNK2(k0)                                                       \
        {                                                                        \
            _Pragma("unroll")                                                    \
            for (int r = 0; r < 4; ++r) {                                        \
                int idx = tid + r * 256;                                         \
                int row = idx >> 3, kq = (idx & 7) * 4;                          \
                xr[r] = *(const float4*)(X + (size_t)(m0 + row) * ldx + (k0) + kq); \
                wr[r] = *(const float4*)(W + (size_t)(n0 + row) * ldw + (k0) + kq); \
            }                                                                    \
        }
    #define STASH2()                                                             \
        {                                                                        \
            _Pragma("unroll")                                                    \
            for (int r = 0; r < 4; ++r) {                                        \
                int idx = tid + r * 256;                                         \
                int row = idx >> 3, kq = (idx & 7) * 4;                          \
                Xs[kq + 0][row] = xr[r].x; Xs[kq + 1][row] = xr[r].y;            \
                Xs[kq + 2][row] = xr[r].z; Xs[kq + 3][row] = xr[r].w;            \
                Ws[kq + 0][row] = wr[r].x; Ws[kq + 1][row] = wr[r].y;            \
                Ws[kq + 2][row] = wr[r].z; Ws[kq + 3][row] = wr[r].w;            \
            }                                                                    \
        }

    LOADCHUNK2(0);
    STASH2();
    __syncthreads();

    for (int k0 = 0; k0 < K; k0 += 32) {
        bool last = (k0 + 32 >= K);
        if (!last) LOADCHUNK2(k0 + 32);
        #pragma unroll
        for (int kk = 0; kk < 32; ++kk) {
            float4 a0 = *(const float4*)&Xs[kk][ty * 4];
            float4 a1 = *(const float4*)&Xs[kk][64 + ty * 4];
            float4 b0 = *(const float4*)&Ws[kk][tx * 4];
            float4 b1 = *(const float4*)&Ws[kk][64 + tx * 4];
            float av[8] = {a0.x, a0.y, a0.z, a0.w, a1.x, a1.y, a1.z, a1.w};
            float bv[8] = {b0.x, b0.y, b0.z, b0.w, b1.x, b1.y, b1.z, b1.w};
            #pragma unroll
            for (int i = 0; i < 8; ++i)
                #pragma unroll
                for (int j = 0; j < 8; ++j)
                    acc[i][j] = fmaf(av[i], bv[j], acc[i][j]);
        }
        __syncthreads();
        if (!last) {
            STASH2();
            __syncthreads();
        }
    }

    float4 bb0 = {0, 0, 0, 0}, bb1 = {0, 0, 0, 0};
    if (mode & 1) {
        bb0 = *(const float4*)(bias + n0 + tx * 4);
        bb1 = *(const float4*)(bias + n0 + 64 + tx * 4);
    }
    #pragma unroll
    for (int i = 0; i < 8; ++i) {
        int r = m0 + ((i < 4) ? (ty * 4 + i) : (64 + ty * 4 + (i - 4)));
        #pragma unroll
        for (int h = 0; h < 2; ++h) {
            int c0 = n0 + h * 64 + tx * 4;
            const float* bp = h ? (const float*)&bb1 : (const float*)&bb0;
            float v[4];
            #pragma unroll
            for (int j = 0; j < 4; ++j) {
                v[j] = acc[i][h * 4 + j];
                if (mode & 1) v[j] += bp[j];
            }
            if (mode & 8) {
                uchar4 mo;
                mo.x = v[0] > 0.0f; mo.y = v[1] > 0.0f; mo.z = v[2] > 0.0f; mo.w = v[3] > 0.0f;
                *(uchar4*)&maskOut[(size_t)r * N + c0] = mo;
            }
            if (mode & 16) {
                uchar4 mm = *(const uchar4*)&maskMul[(size_t)r * N + c0];
                v[0] *= mm.x; v[1] *= mm.y; v[2] *= mm.z; v[3] *= mm.w;
            }
            if (mode & 2) {
                #pragma unroll
                for (int j = 0; j < 4; ++j) v[j] = fmaxf(v[j], 0.0f);
            }
            if (mode & 4) {
                float4 st = {v[0], v[1], v[2], v[3]};
                *(float4*)(C + (size_t)r * ldc + c0) = st;
            }
        }
    }
}

// ---------- zng: bf16 MFMA Jacobian chain, 2 batch elems / block (R2-validated) ----------
__global__ __launch_bounds__(512, 2) void zng_kernel(
    const unsigned short* __restrict__ whbf,   // [2][512][512] bf16 (layers 1,2)
    const unsigned short* __restrict__ woutbf, // [64][512] bf16
    const unsigned short* __restrict__ G0tb,   // [64][512] bf16 (G0 transposed)
    const unsigned char* __restrict__ mz1,
    const unsigned char* __restrict__ mz2,
    const unsigned char* __restrict__ mz3,
    float* __restrict__ out)                   // (4096,192), writes cols 128..191
{
    __shared__ __align__(16) unsigned short Rt[2][64 * 520]; // R^T per elem: [n][k]
    __shared__ unsigned char m2s[2][512];
    __shared__ unsigned char m3s[2][512];

    const int b0  = blockIdx.x * 2;
    const int tid = threadIdx.x;

    for (int i = tid; i < 1024; i += 512) {
        int bb = i >> 9, k = i & 511;
        m2s[bb][k] = mz2[(size_t)(b0 + bb) * 512 + k];
        m3s[bb][k] = mz3[(size_t)(b0 + bb) * 512 + k];
    }
    // Phase A: Rt[bb][n][k] = bf16(G0t[n][k]) * D1_bb[k], vectorized x8
    #pragma unroll 4
    for (int i = 0; i < 16; ++i) {
        int c = i * 512 + tid;             // 0..8191
        int bb = c >> 12, rem = c & 4095;
        int n = rem >> 6, k = (rem & 63) * 8;
        s8v g = *(const s8v*)(G0tb + n * 512 + k);
        const unsigned char* mm = mz1 + (size_t)(b0 + bb) * 512 + k;
        unsigned int mlo = *(const unsigned int*)(mm);
        unsigned int mhi = *(const unsigned int*)(mm + 4);
        s8v r;
        #pragma unroll
        for (int j = 0; j < 4; ++j) r[j] = ((mlo >> (8 * j)) & 1) ? g[j] : (short)0;
        #pragma unroll
        for (int j = 0; j < 4; ++j) r[4 + j] = ((mhi >> (8 * j)) & 1) ? g[4 + j] : (short)0;
        *(s8v*)(&Rt[bb][n * 520 + k]) = r;
    }
    __syncthreads();

    const int lane = tid & 63, wave = tid >> 6;
    const int q = lane >> 4, ln = lane & 15;

    // stages: Out_b = Wh[s+1] @ R_b ; R_b <- (D[s+2] (.) Out_b)^T
    for (int s = 0; s < 2; ++s) {
        const unsigned short* A = whbf + (size_t)s * 262144;
        f4v acc[2][4][4];
        #pragma unroll
        for (int bb = 0; bb < 2; ++bb)
            #pragma unroll
            for (int mt = 0; mt < 4; ++mt)
                #pragma unroll
                for (int nt = 0; nt < 4; ++nt)
                    acc[bb][mt][nt] = (f4v)(0.0f);

        s8v af[4], afn[4];
        #pragma unroll
        for (int mt = 0; mt < 4; ++mt)
            af[mt] = *(const s8v*)(A + (size_t)(wave * 64 + mt * 16 + ln) * 512 + q * 8);

        #pragma unroll 2
        for (int ks = 0; ks < 16; ++ks) {
            int kAn = ((ks + 1) & 15) * 32 + q * 8;      // wraps; redundant last load
            #pragma unroll
            for (int mt = 0; mt < 4; ++mt)
                afn[mt] = *(const s8v*)(A + (size_t)(wave * 64 + mt * 16 + ln) * 512 + kAn);

            int kB = ks * 32 + q * 8;
            s8v bfr[2][4];
            #pragma unroll
            for (int bb = 0; bb < 2; ++bb)
                #pragma unroll
                for (int nt = 0; nt < 4; ++nt)
                    bfr[bb][nt] = *(const s8v*)(&Rt[bb][(nt * 16 + ln) * 520 + kB]);

            #pragma unroll
            for (int mt = 0; mt < 4; ++mt)
                #pragma unroll
                for (int nt = 0; nt < 4; ++nt) {
                    acc[0][mt][nt] = __builtin_amdgcn_mfma_f32_16x16x32_bf16(af[mt], bfr[0][nt], acc[0][mt][nt], 0, 0, 0);
                    acc[1][mt][nt] = __builtin_amdgcn_mfma_f32_16x16x32_bf16(af[mt], bfr[1][nt], acc[1][mt][nt], 0, 0, 0);
                }
            #pragma unroll
            for (int mt = 0; mt < 4; ++mt) af[mt] = afn[mt];
        }
        __syncthreads();   // all reads of old Rt done

        const unsigned char (*msk)[512] = (s == 0) ? m2s : m3s;
        #pragma unroll
        for (int bb = 0; bb < 2; ++bb)
            #pragma unroll
            for (int mt = 0; mt < 4; ++mt) {
                int m0 = wave * 64 + mt * 16 + q * 4;
                uchar4 mv = *(const uchar4*)&msk[bb][m0];
                unsigned char mb[4] = {mv.x, mv.y, mv.z, mv.w};
                #pragma unroll
                for (int nt = 0; nt < 4; ++nt) {
                    int n = nt * 16 + ln;
                    s4v pk;
                    #pragma unroll
                    for (int r = 0; r < 4; ++r) {
                        float v = mb[r] ? acc[bb][mt][nt][r] : 0.0f;
                        pk[r] = (short)f2bf(v);
                    }
                    *(s4v*)(&Rt[bb][n * 520 + m0]) = pk;
                }
            }
        __syncthreads();
    }

    // final: g_b = Wout @ R3_b (64x64); zng[m] = ||g_b[m,:]||
    {
        const int bb = wave >> 2, w4 = wave & 3;
        f4v acc3[4];
        #pragma unroll
        for (int nt = 0; nt < 4; ++nt) acc3[nt] = (f4v)(0.0f);
        for (int ks = 0; ks < 16; ++ks) {
            int kA = ks * 32 + q * 8;
            s8v af = *(const s8v*)(woutbf + (size_t)(w4 * 16 + ln) * 512 + kA);
            #pragma unroll
            for (int nt = 0; nt < 4; ++nt) {
                s8v bfr = *(const s8v*)(&Rt[bb][(nt * 16 + ln) * 520 + kA]);
                acc3[nt] = __builtin_amdgcn_mfma_f32_16x16x32_bf16(af, bfr, acc3[nt], 0, 0, 0);
            }
        }
        float ss[4];
        #pragma unroll
        for (int r = 0; r < 4; ++r) {
            float s = 0.f;
            #pragma unroll
            for (int nt = 0; nt < 4; ++nt) { float v = acc3[nt][r]; s = fmaf(v, v, s); }
            ss[r] = s;
        }
        #pragma unroll
        for (int off = 1; off < 16; off <<= 1)
            #pragma unroll
            for (int r = 0; r < 4; ++r)
                ss[r] += __shfl_xor(ss[r], off, 64);
        if (ln == 0) {
            #pragma unroll
            for (int r = 0; r < 4; ++r)
                out[(size_t)(b0 + bb) * 192 + 128 + w4 * 16 + q * 4 + r] = sqrtf(ss[r]);
        }
    }
}

// ---------- host ----------
extern "C" void kernel_launch(void* const* d_in, const int* in_sizes, int n_in,
                              void* d_out, int out_size, void* d_ws, size_t ws_size,
                              hipStream_t stream) {
    const float* x    = (const float*)d_in[0];
    const float* Win  = (const float*)d_in[1];
    const float* bin  = (const float*)d_in[2];
    const float* Wh   = (const float*)d_in[3];
    const float* bh   = (const float*)d_in[4];
    const float* Wout = (const float*)d_in[5];
    const float* bout = (const float*)d_in[6];
    float* out = (float*)d_out;

    char* ws = (char*)d_ws;
    float*          G0     = (float*)(ws);                         // 131072 B
    unsigned short* G0tb   = (unsigned short*)(ws + 131072);       // 65536 B
    unsigned short* whbf   = (unsigned short*)(ws + 196608);       // 1048576 B
    unsigned short* woutbf = (unsigned short*)(ws + 1245184);      // 65536 B
    unsigned char*  masks  = (unsigned char*)(ws + 1310720);       // 6 * 2 MB
    unsigned char* mt1 = masks + 0 * 2097152;
    unsigned char* mt2 = masks + 1 * 2097152;
    unsigned char* mt3 = masks + 2 * 2097152;
    unsigned char* mz1 = masks + 3 * 2097152;
    unsigned char* mz2 = masks + 4 * 2097152;
    unsigned char* mz3 = masks + 5 * 2097152;
    float* bufs = (float*)(ws + 1310720 + 12582912);               // 4 x 8 MB
    float* tA = bufs + 0 * 2097152;
    float* tB = bufs + 1 * 2097152;
    float* zA = bufs + 2 * 2097152;
    float* zB = bufs + 3 * 2097152;

    const float* Wh0 = Wh;
    const float* Wh1 = Wh + 262144;
    const float* Wh2 = Wh + 524288;
    const float* bh0 = bh, *bh1 = bh + 512, *bh2 = bh + 1024;

    conv_bf16<<<dim3(2176), dim3(256), 0, stream>>>(Wh, Wout, whbf, woutbf);
    g0_kernel<<<dim3(512), dim3(64), 0, stream>>>(Wh0, Win, G0, G0tb);

    // big-tile launcher: N multiple of 128
    auto g128 = [&](const float* X0, const float* X1, int ldx,
                    const float* W, int ldw, const float* bias,
                    float* C0, float* C1, int ldc,
                    unsigned char* mo0, unsigned char* mo1,
                    const unsigned char* mm0, const unsigned char* mm1,
                    int K, int N, int mode, int Z) {
        dim3 g(4096 / 128, N / 128, Z);
        gemm_nt128<<<g, dim3(256), 0, stream>>>(X0, X1, ldx, W, ldw, bias, C0, C1, ldc,
                                                mo0, mo1, mm0, mm1, K, N, mode);
    };
    // narrow launcher: N=64 outputs
    auto g64 = [&](const float* X, int ldx, const float* W, int ldw, const float* bias,
                   float* C, int ldc, unsigned char* mo, const unsigned char* mm,
                   int K, int N, int mode) {
        dim3 g(4096 / 128, N / 64, 1);
        gemm_nt<<<g, dim3(256), 0, stream>>>(X, 0, ldx, W, ldw, bias, C, 0, ldc,
                                             mo, 0, mm, 0, K, N, mode);
    };

    // ---- fused forward + delta chain (t: x[:,0:64] ; z: x[:,128:192]) ----
    g128(x, x + 128, 192, Win, 64, bin, tA, zA, 512, 0, 0, 0, 0, 64, 512, 1 | 4, 2);        // h0
    g128(tA, zA, 512, Wh0, 512, bh0,    tB, zB, 512, 0, 0, 0, 0, 512, 512, 1 | 2 | 4, 2);   // h1
    g128(tB, zB, 512, Wh0, 512, bh0,    0, 0, 0, mt1, mz1, 0, 0, 512, 512, 1 | 8, 2);       // delta1
    g128(tB, zB, 512, Wh1, 512, bh1,    tA, zA, 512, 0, 0, 0, 0, 512, 512, 1 | 2 | 4, 2);   // h2
    g128(tA, zA, 512, Wh1, 512, bh1,    0, 0, 0, mt2, mz2, 0, 0, 512, 512, 1 | 8, 2);       // delta2
    g128(tA, zA, 512, Wh2, 512, bh2,    tB, zB, 512, 0, 0, 0, 0, 512, 512, 1 | 2 | 4, 2);   // h3
    g128(tB, zB, 512, Wh2, 512, bh2,    0, 0, 0, mt3, mz3, 0, 0, 512, 512, 1 | 8, 2);       // delta3

    // ---- zng (z-branch Jacobian row norms) ----
    zng_kernel<<<dim3(2048), dim3(512), 0, stream>>>(whbf, woutbf, G0tb, mz1, mz2, mz3, out);

    // ---- h_out (t-branch forward output) ----
    g64(tB, 512, Wout, 512, bout, out, 192, 0, 0, 512, 64, 1 | 4);                          // cols 0..63

    // ---- h_dot chain: V = D (.) (W v), contracted with xtdot up-front ----
    g128(x + 64, 0, 192, G0, 64, 0, tA, 0, 512, 0, 0, mt1, 0, 64, 512, 4 | 16, 1);          // V1
    g128(tA, 0, 512, Wh1, 512, 0, zA, 0, 512, 0, 0, mt2, 0, 512, 512, 4 | 16, 1);           // V2
    g128(zA, 0, 512, Wh2, 512, 0, zB, 0, 512, 0, 0, mt3, 0, 512, 512, 4 | 16, 1);           // V3
    g64(zB, 512, Wout, 512, 0, out + 64, 192, 0, 0, 512, 64, 4);                            // h_dot
}

// Round 6
// 956.424 us; speedup vs baseline: 1.1565x; 1.0771x over previous
//
#include <hip/hip_runtime.h>
#include <math.h>

typedef __attribute__((ext_vector_type(8))) short s8v;   // 8 x bf16
typedef __attribute__((ext_vector_type(4))) short s4v;   // 4 x bf16
typedef __attribute__((ext_vector_type(4))) float f4v;   // 4 x f32

static __device__ __forceinline__ unsigned short f2bf(float f) {
    union { float f; unsigned int u; } v; v.f = f;
    unsigned int r = v.u + 0x7fffu + ((v.u >> 16) & 1u);   // RNE
    return (unsigned short)(r >> 16);
}

// ---------- weight conversion: Wh[1],Wh[2] and Wout to bf16 ----------
__global__ void conv_bf16(const float* __restrict__ Wh, const float* __restrict__ Wout,
                          unsigned short* __restrict__ whbf, unsigned short* __restrict__ woutbf) {
    int i = blockIdx.x * 256 + threadIdx.x;
    if (i < 524288) {
        whbf[i] = f2bf(Wh[262144 + i]);            // layers 1,2 contiguous
    } else if (i < 524288 + 32768) {
        int j = i - 524288;
        woutbf[j] = f2bf(Wout[j]);
    }
}

// ---------- G0 = Wh0 @ W_in (512x64) fp32, + transposed bf16 copy ----------
__global__ void g0_kernel(const float* __restrict__ Wh0, const float* __restrict__ Win,
                          float* __restrict__ G0, unsigned short* __restrict__ G0tb) {
    int i = blockIdx.x;      // 0..511
    int j = threadIdx.x;     // 0..63
    float acc = 0.f;
    for (int k = 0; k < 512; ++k)
        acc = fmaf(Wh0[i * 512 + k], Win[k * 64 + j], acc);
    G0[i * 64 + j] = acc;
    G0tb[j * 512 + i] = f2bf(acc);
}

// ======== fp32 GEMM 128x64 tile (R4-validated), branch-fused over blockIdx.z ========
// mode bits: 1=+bias  2=relu  4=write C  8=write mask(u8)  16=mul by maskMul(u8)
__global__ __launch_bounds__(256) void gemm_nt(
    const float* __restrict__ X0, const float* __restrict__ X1, int ldx,
    const float* __restrict__ W, int ldw,
    const float* __restrict__ bias,
    float* __restrict__ C0, float* __restrict__ C1, int ldc,
    unsigned char* __restrict__ mo0, unsigned char* __restrict__ mo1,
    const unsigned char* __restrict__ mm0, const unsigned char* __restrict__ mm1,
    int K, int N, int mode)
{
    const int z = blockIdx.z;
    const float* __restrict__ X = z ? X1 : X0;
    float* __restrict__ C = z ? C1 : C0;
    unsigned char* __restrict__ maskOut = z ? mo1 : mo0;
    const unsigned char* __restrict__ maskMul = z ? mm1 : mm0;

    __shared__ float Xs[32][132];
    __shared__ float Ws[32][68];
    const int tid = threadIdx.x;
    const int m0 = blockIdx.x * 128;
    const int n0 = blockIdx.y * 64;
    const int tx = tid & 15, ty = tid >> 4;
    float acc[8][4] = {};

    float4 xr[4], wr[2];

    #define LOADCHUNK(k0)                                                        \
        {                                                                        \
            _Pragma("unroll")                                                    \
            for (int r = 0; r < 4; ++r) {                                        \
                int idx = tid + r * 256;                                         \
                int row = idx >> 3, kq = (idx & 7) * 4;                          \
                xr[r] = *(const float4*)(X + (size_t)(m0 + row) * ldx + (k0) + kq); \
            }                                                                    \
            _Pragma("unroll")                                                    \
            for (int r = 0; r < 2; ++r) {                                        \
                int idx = tid + r * 256;                                         \
                int row = idx >> 3, kq = (idx & 7) * 4;                          \
                wr[r] = *(const float4*)(W + (size_t)(n0 + row) * ldw + (k0) + kq); \
            }                                                                    \
        }
    #define STASH()                                                              \
        {                                                                        \
            _Pragma("unroll")                                                    \
            for (int r = 0; r < 4; ++r) {                                        \
                int idx = tid + r * 256;                                         \
                int row = idx >> 3, kq = (idx & 7) * 4;                          \
                Xs[kq + 0][row] = xr[r].x; Xs[kq + 1][row] = xr[r].y;            \
                Xs[kq + 2][row] = xr[r].z; Xs[kq + 3][row] = xr[r].w;            \
            }                                                                    \
            _Pragma("unroll")                                                    \
            for (int r = 0; r < 2; ++r) {                                        \
                int idx = tid + r * 256;                                         \
                int row = idx >> 3, kq = (idx & 7) * 4;                          \
                Ws[kq + 0][row] = wr[r].x; Ws[kq + 1][row] = wr[r].y;            \
                Ws[kq + 2][row] = wr[r].z; Ws[kq + 3][row] = wr[r].w;            \
            }                                                                    \
        }

    LOADCHUNK(0);
    STASH();
    __syncthreads();

    for (int k0 = 0; k0 < K; k0 += 32) {
        bool last = (k0 + 32 >= K);
        if (!last) LOADCHUNK(k0 + 32);
        #pragma unroll
        for (int kk = 0; kk < 32; ++kk) {
            float4 a0 = *(const float4*)&Xs[kk][ty * 4];
            float4 a1 = *(const float4*)&Xs[kk][64 + ty * 4];
            float4 b0 = *(const float4*)&Ws[kk][tx * 4];
            float av[8] = {a0.x, a0.y, a0.z, a0.w, a1.x, a1.y, a1.z, a1.w};
            float bv[4] = {b0.x, b0.y, b0.z, b0.w};
            #pragma unroll
            for (int i = 0; i < 8; ++i)
                #pragma unroll
                for (int j = 0; j < 4; ++j)
                    acc[i][j] = fmaf(av[i], bv[j], acc[i][j]);
        }
        __syncthreads();
        if (!last) {
            STASH();
            __syncthreads();
        }
    }

    float4 bb = {0, 0, 0, 0};
    if (mode & 1) bb = *(const float4*)(bias + n0 + tx * 4);
    const int c0 = n0 + tx * 4;
    #pragma unroll
    for (int i = 0; i < 8; ++i) {
        int r = m0 + ((i < 4) ? (ty * 4 + i) : (64 + ty * 4 + (i - 4)));
        float v[4];
        #pragma unroll
        for (int j = 0; j < 4; ++j) {
            v[j] = acc[i][j];
            if (mode & 1) v[j] += ((const float*)&bb)[j];
        }
        if (mode & 8) {
            uchar4 mo;
            mo.x = v[0] > 0.0f; mo.y = v[1] > 0.0f; mo.z = v[2] > 0.0f; mo.w = v[3] > 0.0f;
            *(uchar4*)&maskOut[(size_t)r * N + c0] = mo;
        }
        if (mode & 16) {
            uchar4 mm = *(const uchar4*)&maskMul[(size_t)r * N + c0];
            v[0] *= mm.x; v[1] *= mm.y; v[2] *= mm.z; v[3] *= mm.w;
        }
        if (mode & 2) {
            #pragma unroll
            for (int j = 0; j < 4; ++j) v[j] = fmaxf(v[j], 0.0f);
        }
        if (mode & 4) {
            float4 st = {v[0], v[1], v[2], v[3]};
            *(float4*)(C + (size_t)r * ldc + c0) = st;
        }
    }
}

// ---------- zng: bf16 MFMA Jacobian chain, 2 elems/block, XOR-swizzled LDS ----------
// Rt chunk layout: row n (0..63), 16B-chunk c (0..63) stored at n*512 + (c^(n&7))*8.
// All four access sites use the same f(n,c) => consistent by construction.
__global__ __launch_bounds__(512, 2) void zng_kernel(
    const unsigned short* __restrict__ whbf,   // [2][512][512] bf16 (layers 1,2)
    const unsigned short* __restrict__ woutbf, // [64][512] bf16
    const unsigned short* __restrict__ G0tb,   // [64][512] bf16 (G0 transposed)
    const unsigned char* __restrict__ mz1,
    const unsigned char* __restrict__ mz2,
    const unsigned char* __restrict__ mz3,
    float* __restrict__ out)                   // (4096,192), writes cols 128..191
{
    __shared__ __align__(16) unsigned short Rt[2][64 * 512]; // swizzled, no pad
    __shared__ unsigned char m2s[2][512];
    __shared__ unsigned char m3s[2][512];

    const int b0  = blockIdx.x * 2;
    const int tid = threadIdx.x;

    for (int i = tid; i < 1024; i += 512) {
        int bb = i >> 9, k = i & 511;
        m2s[bb][k] = mz2[(size_t)(b0 + bb) * 512 + k];
        m3s[bb][k] = mz3[(size_t)(b0 + bb) * 512 + k];
    }
    // Phase A: Rt[bb][n][swz(c)] = bf16(G0t[n][c*8..]) * D1_bb
    #pragma unroll 4
    for (int i = 0; i < 16; ++i) {
        int c = i * 512 + tid;             // 0..8191
        int bb = c >> 12, rem = c & 4095;
        int n = rem >> 6, ch = rem & 63;
        int k = ch * 8;
        s8v g = *(const s8v*)(G0tb + n * 512 + k);
        const unsigned char* mm = mz1 + (size_t)(b0 + bb) * 512 + k;
        unsigned int mlo = *(const unsigned int*)(mm);
        unsigned int mhi = *(const unsigned int*)(mm + 4);
        s8v r;
        #pragma unroll
        for (int j = 0; j < 4; ++j) r[j] = ((mlo >> (8 * j)) & 1) ? g[j] : (short)0;
        #pragma unroll
        for (int j = 0; j < 4; ++j) r[4 + j] = ((mhi >> (8 * j)) & 1) ? g[4 + j] : (short)0;
        *(s8v*)(&Rt[bb][n * 512 + ((ch ^ (n & 7)) << 3)]) = r;
    }
    __syncthreads();

    const int lane = tid & 63, wave = tid >> 6;
    const int q = lane >> 4, ln = lane & 15;
    const int ln7 = ln & 7;

    // stages: Out_b = Wh[s+1] @ R_b ; R_b <- (D[s+2] (.) Out_b)^T
    for (int s = 0; s < 2; ++s) {
        const unsigned short* A = whbf + (size_t)s * 262144;
        f4v acc[2][4][4];
        #pragma unroll
        for (int bb = 0; bb < 2; ++bb)
            #pragma unroll
            for (int mt = 0; mt < 4; ++mt)
                #pragma unroll
                for (int nt = 0; nt < 4; ++nt)
                    acc[bb][mt][nt] = (f4v)(0.0f);

        s8v af[4], afn[4];
        #pragma unroll
        for (int mt = 0; mt < 4; ++mt)
            af[mt] = *(const s8v*)(A + (size_t)(wave * 64 + mt * 16 + ln) * 512 + q * 8);

        #pragma unroll 2
        for (int ks = 0; ks < 16; ++ks) {
            int kAn = ((ks + 1) & 15) * 32 + q * 8;      // wraps; redundant last load
            #pragma unroll
            for (int mt = 0; mt < 4; ++mt)
                afn[mt] = *(const s8v*)(A + (size_t)(wave * 64 + mt * 16 + ln) * 512 + kAn);

            int cB = (ks * 4 + q) ^ ln7;                 // swizzled chunk index
            s8v bfr[2][4];
            #pragma unroll
            for (int bb = 0; bb < 2; ++bb)
                #pragma unroll
                for (int nt = 0; nt < 4; ++nt)
                    bfr[bb][nt] = *(const s8v*)(&Rt[bb][(nt * 16 + ln) * 512 + (cB << 3)]);

            #pragma unroll
            for (int mt = 0; mt < 4; ++mt)
                #pragma unroll
                for (int nt = 0; nt < 4; ++nt) {
                    acc[0][mt][nt] = __builtin_amdgcn_mfma_f32_16x16x32_bf16(af[mt], bfr[0][nt], acc[0][mt][nt], 0, 0, 0);
                    acc[1][mt][nt] = __builtin_amdgcn_mfma_f32_16x16x32_bf16(af[mt], bfr[1][nt], acc[1][mt][nt], 0, 0, 0);
                }
            #pragma unroll
            for (int mt = 0; mt < 4; ++mt) af[mt] = afn[mt];
        }
        __syncthreads();   // all reads of old Rt done

        const unsigned char (*msk)[512] = (s == 0) ? m2s : m3s;
        #pragma unroll
        for (int bb = 0; bb < 2; ++bb)
            #pragma unroll
            for (int mt = 0; mt < 4; ++mt) {
                int m0 = wave * 64 + mt * 16 + q * 4;    // k-position in new R
                int cw = (wave * 8 + mt * 2 + (q >> 1)); // chunk of m0
                int wo = (q & 1) * 4;                    // short offset in chunk
                uchar4 mv = *(const uchar4*)&msk[bb][m0];
                unsigned char mb[4] = {mv.x, mv.y, mv.z, mv.w};
                #pragma unroll
                for (int nt = 0; nt < 4; ++nt) {
                    int n = nt * 16 + ln;
                    s4v pk;
                    #pragma unroll
                    for (int r = 0; r < 4; ++r) {
                        float v = mb[r] ? acc[bb][mt][nt][r] : 0.0f;
                        pk[r] = (short)f2bf(v);
                    }
                    *(s4v*)(&Rt[bb][n * 512 + ((cw ^ ln7) << 3) + wo]) = pk;
                }
            }
        __syncthreads();
    }

    // final: g_b = Wout @ R3_b (64x64); zng[m] = ||g_b[m,:]||
    {
        const int bb = wave >> 2, w4 = wave & 3;
        f4v acc3[4];
        #pragma unroll
        for (int nt = 0; nt < 4; ++nt) acc3[nt] = (f4v)(0.0f);
        for (int ks = 0; ks < 16; ++ks) {
            int kA = ks * 32 + q * 8;
            int cB = (ks * 4 + q) ^ ln7;
            s8v af = *(const s8v*)(woutbf + (size_t)(w4 * 16 + ln) * 512 + kA);
            #pragma unroll
            for (int nt = 0; nt < 4; ++nt) {
                s8v bfr = *(const s8v*)(&Rt[bb][(nt * 16 + ln) * 512 + (cB << 3)]);
                acc3[nt] = __builtin_amdgcn_mfma_f32_16x16x32_bf16(af, bfr, acc3[nt], 0, 0, 0);
            }
        }
        float ss[4];
        #pragma unroll
        for (int r = 0; r < 4; ++r) {
            float s = 0.f;
            #pragma unroll
            for (int nt = 0; nt < 4; ++nt) { float v = acc3[nt][r]; s = fmaf(v, v, s); }
            ss[r] = s;
        }
        #pragma unroll
        for (int off = 1; off < 16; off <<= 1)
            #pragma unroll
            for (int r = 0; r < 4; ++r)
                ss[r] += __shfl_xor(ss[r], off, 64);
        if (ln == 0) {
            #pragma unroll
            for (int r = 0; r < 4; ++r)
                out[(size_t)(b0 + bb) * 192 + 128 + w4 * 16 + q * 4 + r] = sqrtf(ss[r]);
        }
    }
}

// ---------- host ----------
extern "C" void kernel_launch(void* const* d_in, const int* in_sizes, int n_in,
                              void* d_out, int out_size, void* d_ws, size_t ws_size,
                              hipStream_t stream) {
    const float* x    = (const float*)d_in[0];
    const float* Win  = (const float*)d_in[1];
    const float* bin  = (const float*)d_in[2];
    const float* Wh   = (const float*)d_in[3];
    const float* bh   = (const float*)d_in[4];
    const float* Wout = (const float*)d_in[5];
    const float* bout = (const float*)d_in[6];
    float* out = (float*)d_out;

    char* ws = (char*)d_ws;
    float*          G0     = (float*)(ws);                         // 131072 B
    unsigned short* G0tb   = (unsigned short*)(ws + 131072);       // 65536 B
    unsigned short* whbf   = (unsigned short*)(ws + 196608);       // 1048576 B
    unsigned short* woutbf = (unsigned short*)(ws + 1245184);      // 65536 B
    unsigned char*  masks  = (unsigned char*)(ws + 1310720);       // 6 * 2 MB
    unsigned char* mt1 = masks + 0 * 2097152;
    unsigned char* mt2 = masks + 1 * 2097152;
    unsigned char* mt3 = masks + 2 * 2097152;
    unsigned char* mz1 = masks + 3 * 2097152;
    unsigned char* mz2 = masks + 4 * 2097152;
    unsigned char* mz3 = masks + 5 * 2097152;
    float* bufs = (float*)(ws + 1310720 + 12582912);               // 4 x 8 MB
    float* tA = bufs + 0 * 2097152;
    float* tB = bufs + 1 * 2097152;
    float* zA = bufs + 2 * 2097152;
    float* zB = bufs + 3 * 2097152;

    const float* Wh0 = Wh;
    const float* Wh1 = Wh + 262144;
    const float* Wh2 = Wh + 524288;
    const float* bh0 = bh, *bh1 = bh + 512, *bh2 = bh + 1024;

    conv_bf16<<<dim3(2176), dim3(256), 0, stream>>>(Wh, Wout, whbf, woutbf);
    g0_kernel<<<dim3(512), dim3(64), 0, stream>>>(Wh0, Win, G0, G0tb);

    // fused 2-branch GEMM launcher (Z=2) and single-branch (Z=1)
    auto gemm2 = [&](const float* X0, const float* X1, int ldx,
                     const float* W, int ldw, const float* bias,
                     float* C0, float* C1, int ldc,
                     unsigned char* mo0, unsigned char* mo1,
                     const unsigned char* mm0, const unsigned char* mm1,
                     int K, int N, int mode) {
        dim3 g(4096 / 128, N / 64, 2);
        gemm_nt<<<g, dim3(256), 0, stream>>>(X0, X1, ldx, W, ldw, bias, C0, C1, ldc,
                                             mo0, mo1, mm0, mm1, K, N, mode);
    };
    auto gemm1 = [&](const float* X, int ldx, const float* W, int ldw, const float* bias,
                     float* C, int ldc, unsigned char* mo, const unsigned char* mm,
                     int K, int N, int mode) {
        dim3 g(4096 / 128, N / 64, 1);
        gemm_nt<<<g, dim3(256), 0, stream>>>(X, 0, ldx, W, ldw, bias, C, 0, ldc,
                                             mo, 0, mm, 0, K, N, mode);
    };

    // ---- fused forward + delta chain (t: x[:,0:64] ; z: x[:,128:192]) ----
    gemm2(x, x + 128, 192, Win, 64, bin, tA, zA, 512, 0, 0, 0, 0, 64, 512, 1 | 4);          // h0
    gemm2(tA, zA, 512, Wh0, 512, bh0,    tB, zB, 512, 0, 0, 0, 0, 512, 512, 1 | 2 | 4);     // h1
    gemm2(tB, zB, 512, Wh0, 512, bh0,    0, 0, 0, mt1, mz1, 0, 0, 512, 512, 1 | 8);         // delta1
    gemm2(tB, zB, 512, Wh1, 512, bh1,    tA, zA, 512, 0, 0, 0, 0, 512, 512, 1 | 2 | 4);     // h2
    gemm2(tA, zA, 512, Wh1, 512, bh1,    0, 0, 0, mt2, mz2, 0, 0, 512, 512, 1 | 8);         // delta2
    gemm2(tA, zA, 512, Wh2, 512, bh2,    tB, zB, 512, 0, 0, 0, 0, 512, 512, 1 | 2 | 4);     // h3
    gemm2(tB, zB, 512, Wh2, 512, bh2,    0, 0, 0, mt3, mz3, 0, 0, 512, 512, 1 | 8);         // delta3

    // ---- zng (z-branch Jacobian row norms) ----
    zng_kernel<<<dim3(2048), dim3(512), 0, stream>>>(whbf, woutbf, G0tb, mz1, mz2, mz3, out);

    // ---- h_out (t-branch forward output) ----
    gemm1(tB, 512, Wout, 512, bout, out, 192, 0, 0, 512, 64, 1 | 4);                        // cols 0..63

    // ---- h_dot chain: V = D (.) (W v), contracted with xtdot up-front ----
    gemm1(x + 64, 192, G0, 64, 0, tA, 512, 0, mt1, 64, 512, 4 | 16);                        // V1
    gemm1(tA, 512, Wh1, 512, 0, zA, 512, 0, mt2, 512, 512, 4 | 16);                         // V2
    gemm1(zA, 512, Wh2, 512, 0, zB, 512, 0, mt3, 512, 512, 4 | 16);                         // V3
    gemm1(zB, 512, Wout, 512, 0, out + 64, 192, 0, 0, 512, 64, 4);                          // h_dot
}